// Round 9
// baseline (113.338 us; speedup 1.0000x reference)
//
#include <hip/hip_runtime.h>
#include <math.h>

#define NB 2
#define LL 4096
#define HH 1024
#define DD 64
#define CHK 64
#define NCH 64            /* LL/CHK */
#define BLROWS (NB*LL)    /* 8192 */
#define NCHT (NB*NCH)     /* 128 total chunks */
#define GAMMA 0.96875f

typedef _Float16 f16x8 __attribute__((ext_vector_type(8)));
typedef _Float16 f16x4 __attribute__((ext_vector_type(4)));
typedef float    f32x4 __attribute__((ext_vector_type(4)));

// ---------------------------------------------------------------------------
// Kernel 1: MFMA projection (fp16 split-3), inline W hi/lo split (no prep_w).
// grid 768 = (rowgroup 256) x (colthird 3), 256 thr. Block = 32 rows x 64 cols
// of ONE matrix (Q, K or V per colthird). Outputs:
//   Qr : row-major fp16 [row][d]                      (A-frag source)
//   Kf : frag-ordered K^T slabs [b][d>>3][pos][d&7]   (B-frag source, coalesced)
//   Vf : frag-ordered V^T cells [b][pos>>3][d][pos&7] (B-frag source, coalesced)
// ---------------------------------------------------------------------------
__global__ __launch_bounds__(256) void proj_mfma(
    const float* __restrict__ X, const float* __restrict__ WQ,
    const float* __restrict__ WK, const float* __restrict__ WV,
    _Float16* __restrict__ Qr, _Float16* __restrict__ Kf,
    _Float16* __restrict__ Vf)
{
    __shared__ __align__(16) _Float16 lds[12288];
    _Float16* Xh = lds;              // 2048 halfs
    _Float16* Xl = lds + 2048;       // 2048
    _Float16* Wh = lds + 4096;       // 4096 (4 ct x 2 kt x 64 lanes x 8)
    _Float16* Wl = lds + 8192;       // 4096

    const int tid  = threadIdx.x;
    const int wv   = tid >> 6;
    const int lane = tid & 63;
    const int quad = lane >> 4;
    const int l15  = lane & 15;
    const int r0   = (blockIdx.x & 255) * 32;
    const int cb4  = (blockIdx.x >> 8) * 4;      // coltile base 0,4,8
    const int rt   = wv & 1;
    const int cp   = (wv >> 1) * 2;
    const float* Wm = (cb4 == 0) ? WQ : (cb4 == 4) ? WK : WV;

    // X staging coords
    const int xrow = tid >> 3;              // 0..31
    const int xk8  = (tid & 7) * 8;         // 0..56
    const int xslot = (((xrow >> 4) * 2 + (xk8 >> 5)) * 64 +
                       ((xk8 >> 3) & 3) * 16 + (xrow & 15)) * 8;
    // W slot coords (2 slots/thread)
    int wd[2], wk[2];
#pragma unroll
    for (int i = 0; i < 2; ++i) {
        const int s = tid + i * 256;
        wd[i] = (s >> 7) * 16 + (s & 15);              // d 0..63
        wk[i] = ((s >> 6) & 1) * 32 + ((s >> 4) & 3) * 8;  // k-in-chunk
    }

    f32x4 acc[2];
    acc[0] = (f32x4){0.f, 0.f, 0.f, 0.f};
    acc[1] = (f32x4){0.f, 0.f, 0.f, 0.f};

    float4 pxa, pxb;
    float  pw[2][8];
    {   // prefetch chunk 0
        const float* xp = &X[(size_t)(r0 + xrow) * HH + xk8];
        pxa = *(const float4*)&xp[0];
        pxb = *(const float4*)&xp[4];
#pragma unroll
        for (int i = 0; i < 2; ++i)
#pragma unroll
            for (int j = 0; j < 8; ++j)
                pw[i][j] = Wm[(size_t)(wk[i] + j) * DD + wd[i]];
    }

    for (int ch = 0; ch < 16; ++ch) {
        __syncthreads();
        {   // commit prefetched chunk to LDS (split hi/lo)
            const float xv[8] = {pxa.x, pxa.y, pxa.z, pxa.w,
                                 pxb.x, pxb.y, pxb.z, pxb.w};
            f16x8 hv, lv;
#pragma unroll
            for (int e = 0; e < 8; ++e) {
                const _Float16 h = (_Float16)xv[e];
                hv[e] = h;
                lv[e] = (_Float16)(xv[e] - (float)h);
            }
            *(f16x8*)&Xh[xslot] = hv;
            *(f16x8*)&Xl[xslot] = lv;
#pragma unroll
            for (int i = 0; i < 2; ++i) {
                f16x8 whv, wlv;
#pragma unroll
                for (int j = 0; j < 8; ++j) {
                    const float x = pw[i][j] * 1024.f;
                    const _Float16 h = (_Float16)x;
                    whv[j] = h;
                    wlv[j] = (_Float16)(x - (float)h);
                }
                *(f16x8*)&Wh[(tid + i * 256) * 8] = whv;
                *(f16x8*)&Wl[(tid + i * 256) * 8] = wlv;
            }
        }
        __syncthreads();
        if (ch + 1 < 16) {   // prefetch next chunk
            const float* xp = &X[(size_t)(r0 + xrow) * HH + (ch + 1) * 64 + xk8];
            pxa = *(const float4*)&xp[0];
            pxb = *(const float4*)&xp[4];
            const int kb = (ch + 1) * 64;
#pragma unroll
            for (int i = 0; i < 2; ++i)
#pragma unroll
                for (int j = 0; j < 8; ++j)
                    pw[i][j] = Wm[(size_t)(kb + wk[i] + j) * DD + wd[i]];
        }
#pragma unroll
        for (int kt = 0; kt < 2; ++kt) {
            const f16x8 aH = *(const f16x8*)&Xh[((rt * 2 + kt) * 64 + lane) * 8];
            const f16x8 aL = *(const f16x8*)&Xl[((rt * 2 + kt) * 64 + lane) * 8];
#pragma unroll
            for (int cj = 0; cj < 2; ++cj) {
                const int ctl = cp + cj;
                const f16x8 bh = *(const f16x8*)&Wh[((ctl * 2 + kt) * 64 + lane) * 8];
                const f16x8 bl = *(const f16x8*)&Wl[((ctl * 2 + kt) * 64 + lane) * 8];
                acc[cj] = __builtin_amdgcn_mfma_f32_16x16x32_f16(aH, bh, acc[cj], 0, 0, 0);
                acc[cj] = __builtin_amdgcn_mfma_f32_16x16x32_f16(aH, bl, acc[cj], 0, 0, 0);
                acc[cj] = __builtin_amdgcn_mfma_f32_16x16x32_f16(aL, bh, acc[cj], 0, 0, 0);
            }
        }
    }

    // ---- epilogue: descale + xPos (per-chunk renormalized scale) ----
#pragma unroll
    for (int cj = 0; cj < 2; ++cj) {
        const int ctg = cb4 + cp + cj;
        const f32x4 v = acc[cj];
        const int col = ctg * 16 + l15;
        const int mat = ctg >> 2;            // 0=Q 1=K 2=V
        const int d   = col & 63;
        if (mat < 2) {
            const int i2 = d >> 1;
            const float sv   = (2.f * (float)i2 + 25.6f) / 89.6f;
            const float l2sv = log2f(sv);
            const float ifr  = exp2f(-13.28771237954945f * ((float)i2 / 32.f));
            const float sgn  = (mat == 0) ? 1.f : -1.f;
#pragma unroll
            for (int r = 0; r < 4; ++r) {
                const int row = r0 + rt * 16 + quad * 4 + r;
                const float val = v[r] * (1.f / 1024.f);
                const float p = __shfl_xor(val, 1, 64);
                const float pf  = (float)(row & (LL - 1));   // abs pos
                const float pfs = (float)(row & 63);          // renorm
                const float scl = exp2f(sgn * (pfs * (1.f / 512.f)) * l2sv);
                float s, c;
                sincosf(pf * ifr, &s, &c);
                s *= scl; c *= scl;
                const float o = ((col & 1) == 0) ? val * c - p * s
                                                 : val * c + p * s;
                if (mat == 0) {
                    Qr[(size_t)row * DD + d] = (_Float16)o;
                } else {
                    const int b = row >> 12, posb = row & 4095;
                    Kf[(((size_t)b * 8 + (d >> 3)) * 4096 + posb) * 8 + (d & 7)] =
                        (_Float16)o;
                }
            }
        } else {
            f16x4 vv;
#pragma unroll
            for (int r = 0; r < 4; ++r) vv[r] = (_Float16)(v[r] * (1.f / 1024.f));
            const int row0 = r0 + rt * 16 + quad * 4;
            const int b = row0 >> 12, posb = row0 & 4095;
            *(f16x4*)&Vf[(((size_t)b * 512 + (posb >> 3)) * 64 + d) * 8 + (posb & 7)] = vv;
        }
    }
}

// ---------------------------------------------------------------------------
// Kernel 2: chunk output, direct cross-attention over prev 8 chunks (no U/T).
//   S[n][m]      = (Q~.K~_m) pwl[n-m] (n>=m)                     m in chunk c
//   S[n][64+mc]  = (Q~.K''_mc) * pwl[na],  K'' = K~ * g^(64D-mq) * sv_d^(D/8)
//   out = S @ V_all  (576-k MFMA pass; B-frags coalesced from Vf)
// grid 256 = (chunk 128) x (n-half 2), 256 thr. LDS ~38.5 KB.
// ---------------------------------------------------------------------------
__global__ __launch_bounds__(256) void chunk_out(
    const _Float16* __restrict__ Qr, const _Float16* __restrict__ Kf,
    const _Float16* __restrict__ Vf, float* __restrict__ out)
{
    __shared__ __align__(16) unsigned char smraw[38464];
    _Float16* Sb  = (_Float16*)smraw;             // 32 x 580 f16 = 37120 B
    _Float16* svp = (_Float16*)(smraw + 37120);   // 512 f16 = 1024 B
    float*    pwl = (float*)(smraw + 38144);      // 65 f32

    const int tid   = threadIdx.x;
    const int bc    = blockIdx.x;
    const int chunk = bc >> 1;
    const int nh    = (bc & 1) * 32;
    const int w     = tid >> 6;
    const int lane  = tid & 63;
    const int quad  = lane >> 4;
    const int l15   = lane & 15;
    const int mt    = w >> 1;
    const int npair = (w & 1) * 2;
    const int cloc  = chunk & 63;
    const int bB    = chunk >> 6;
    const size_t rowbase = (size_t)chunk * CHK + nh;
    const float l2g = log2f(GAMMA);

    if (tid < 65) pwl[tid] = exp2f((float)tid * l2g);
#pragma unroll
    for (int e = 0; e < 2; ++e) {     // svp[(D-1)*64 + d] = sv_d^(D/8)
        const int idx = tid + e * 256;
        const int dl  = (idx >> 6) + 1;
        const int dd  = idx & 63;
        const float sv = (2.f * (float)(dd >> 1) + 25.6f) / 89.6f;
        svp[idx] = (_Float16)exp2f(0.125f * (float)dl * log2f(sv));
    }

    // A-frags (Q~ rows of this block)
    f16x8 aQ[2];
#pragma unroll
    for (int ks = 0; ks < 2; ++ks)
        aQ[ks] = *(const f16x8*)&Qr[(rowbase + mt * 16 + l15) * DD +
                                    ks * 32 + quad * 8];
    __syncthreads();   // svp, pwl ready

    // ---- phase A intra ----
    f32x4 sA[2] = {(f32x4){0.f,0.f,0.f,0.f}, (f32x4){0.f,0.f,0.f,0.f}};
#pragma unroll
    for (int nt = 0; nt < 2; ++nt) {
        const int posb = cloc * 64 + (npair + nt) * 16 + l15;
#pragma unroll
        for (int ks = 0; ks < 2; ++ks) {
            const f16x8 bK = *(const f16x8*)&Kf[(((size_t)bB * 8 + ks * 4 + quad)
                                                * 4096 + posb) * 8];
            sA[nt] = __builtin_amdgcn_mfma_f32_16x16x32_f16(aQ[ks], bK, sA[nt], 0, 0, 0);
        }
    }
#pragma unroll
    for (int nt = 0; nt < 2; ++nt) {
        const int m = (npair + nt) * 16 + l15;
#pragma unroll
        for (int r = 0; r < 4; ++r) {
            const int nl = mt * 16 + quad * 4 + r;
            const int n64 = nh + nl;
            const float val = (n64 >= m) ? sA[nt][r] * pwl[n64 - m] : 0.f;
            Sb[nl * 580 + m] = (_Float16)val;
        }
    }

    // ---- phase A cross: 16 jtiles/wave over prev 512 keys ----
    for (int jc = (w & 1); jc < 32; jc += 2) {
        const int dlt = 8 - (jc >> 2);                 // chunk distance 1..8
        const bool valid = (dlt <= cloc);
        const int mq = (jc * 16 + l15) & 63;
        const float gl = valid ? exp2f((float)(64 * dlt - mq) * l2g) : 0.f;
        const _Float16 glh = (_Float16)gl;
        const int cs = valid ? (chunk - dlt) : chunk;
        const int posb = (cs & 63) * 64 + mq;
        f32x4 sc4 = (f32x4){0.f, 0.f, 0.f, 0.f};
#pragma unroll
        for (int ks = 0; ks < 2; ++ks) {
            const f16x8 bk = *(const f16x8*)&Kf[(((size_t)bB * 8 + ks * 4 + quad)
                                                * 4096 + posb) * 8];
            const f16x8 sv8 = *(const f16x8*)&svp[(dlt - 1) * 64 + ks * 32 + quad * 8];
            f16x8 b2;
#pragma unroll
            for (int j = 0; j < 8; ++j) b2[j] = bk[j] * glh * sv8[j];
            sc4 = __builtin_amdgcn_mfma_f32_16x16x32_f16(aQ[ks], b2, sc4, 0, 0, 0);
        }
#pragma unroll
        for (int r = 0; r < 4; ++r) {
            const int nl = mt * 16 + quad * 4 + r;
            const int na = nh + nl;
            Sb[nl * 580 + 64 + jc * 16 + l15] = (_Float16)(sc4[r] * pwl[na]);
        }
    }
    __syncthreads();

    // ---- phase B: out = S @ V_all (576 k) ----
    f32x4 oA[2] = {(f32x4){0.f,0.f,0.f,0.f}, (f32x4){0.f,0.f,0.f,0.f}};
    for (int ks5 = 0; ks5 < 18; ++ks5) {
        const f16x8 aS = *(const f16x8*)&Sb[(mt * 16 + l15) * 580 +
                                            ks5 * 32 + quad * 8];
        const int m0 = ks5 * 32 + quad * 8;
        int gr;
        if (ks5 < 2) {
            gr = chunk * 64 + m0;
        } else {
            const int mc = m0 - 64;
            int cs2 = chunk - 8 + (mc >> 6);
            if (cs2 < (chunk & ~63)) cs2 = chunk;      // invalid -> S cols are 0
            gr = cs2 * 64 + (mc & 63);
        }
        const int b2 = gr >> 12, pb = gr & 4095;
        const size_t vb = ((size_t)b2 * 512 + (pb >> 3)) * 64;
#pragma unroll
        for (int t = 0; t < 2; ++t) {
            const int dp = (npair + t) * 16 + l15;
            const f16x8 bV = *(const f16x8*)&Vf[(vb + dp) * 8];
            oA[t] = __builtin_amdgcn_mfma_f32_16x16x32_f16(aS, bV, oA[t], 0, 0, 0);
        }
    }
#pragma unroll
    for (int t = 0; t < 2; ++t)
#pragma unroll
        for (int r = 0; r < 4; ++r)
            out[(rowbase + mt * 16 + quad * 4 + r) * DD +
                (npair + t) * 16 + l15] = oA[t][r];
}

// ---------------------------------------------------------------------------
extern "C" void kernel_launch(void* const* d_in, const int* in_sizes, int n_in,
                              void* d_out, int out_size, void* d_ws, size_t ws_size,
                              hipStream_t stream)
{
    const float* X  = (const float*)d_in[0];
    const float* WQ = (const float*)d_in[1];
    const float* WK = (const float*)d_in[2];
    const float* WV = (const float*)d_in[3];
    float* outp = (float*)d_out;

    _Float16* Qr = (_Float16*)d_ws;                  // 524288 h
    _Float16* Kf = Qr + (size_t)BLROWS * DD;         // 524288 h
    _Float16* Vf = Kf + (size_t)BLROWS * DD;         // 524288 h
    // total 3 MB

    hipLaunchKernelGGL(proj_mfma, dim3(768), dim3(256), 0, stream,
                       X, WQ, WK, WV, Qr, Kf, Vf);
    hipLaunchKernelGGL(chunk_out, dim3(2 * NCHT), dim3(256), 0, stream,
                       Qr, Kf, Vf, outp);
}

// Round 10
// 109.619 us; speedup vs baseline: 1.0339x; 1.0339x over previous
//
#include <hip/hip_runtime.h>
#include <math.h>

#define NB 2
#define LL 4096
#define HH 1024
#define DD 64
#define CHK 64
#define NCH 64            /* LL/CHK */
#define BLROWS (NB*LL)    /* 8192 */
#define NCHT (NB*NCH)     /* 128 total chunks */
#define GAMMA 0.96875f

typedef _Float16 f16x8 __attribute__((ext_vector_type(8)));
typedef _Float16 f16x4 __attribute__((ext_vector_type(4)));
typedef float    f32x4 __attribute__((ext_vector_type(4)));

#define WCH 12288   /* W frag layout: [16 kchunks][12 ct][2 kt][64 lanes][8] */
#define SBS 584     /* Sb row stride (f16), padded for bank spread */

// ---------------------------------------------------------------------------
// Kernel 0: split W (scaled 2^10) into fp16 hi/lo, fragment order.
// grid 96 x 256 (24576 f16x8 slots), coalesced stores.
// ---------------------------------------------------------------------------
__global__ __launch_bounds__(256) void prep_w(
    const float* __restrict__ WQ, const float* __restrict__ WK,
    const float* __restrict__ WV, _Float16* __restrict__ Whg,
    _Float16* __restrict__ Wlg)
{
    const unsigned t = blockIdx.x * 256 + threadIdx.x;   // 0..24575
    const unsigned kchunk = t / 1536u;
    const unsigned s = t - kchunk * 1536u;
    const int ct2  = s >> 6;            // (n16)*2 + kt
    const int lane = s & 63;
    const int n16  = ct2 >> 1;
    const int kt   = ct2 & 1;
    const int quad = lane >> 4;
    const int n    = n16 * 16 + (lane & 15);
    const int k0   = (int)kchunk * 64 + kt * 32 + quad * 8;
    const int m    = n >> 6;
    const int d    = n & 63;
    const float* Wm = (m == 0) ? WQ : (m == 1) ? WK : WV;
    f16x8 hv, lv;
#pragma unroll
    for (int j = 0; j < 8; ++j) {
        const float x = Wm[(size_t)(k0 + j) * DD + d] * 1024.f;
        const _Float16 h = (_Float16)x;
        hv[j] = h;
        lv[j] = (_Float16)(x - (float)h);
    }
    *(f16x8*)&Whg[(size_t)t * 8] = hv;
    *(f16x8*)&Wlg[(size_t)t * 8] = lv;
}

// ---------------------------------------------------------------------------
// Kernel 1: MFMA projection (fp16 split-3) + xPos epilogue.
// grid 768 = (rowgroup 256) x (colthird 3), 256 thr. Block = 32 rows x 64 cols.
// B-frags from frag-ordered Whg/Wlg (LDS-staged, reg-prefetch pipelined).
// Outputs: Qr row-major fp16; Kf frag slabs [b][d>>3][pos][d&7];
//          Vf frag cells [b][pos>>3][d][pos&7].
// ---------------------------------------------------------------------------
__global__ __launch_bounds__(256) void proj_mfma(
    const float* __restrict__ X, const _Float16* __restrict__ Whg,
    const _Float16* __restrict__ Wlg, _Float16* __restrict__ Qr,
    _Float16* __restrict__ Kf, _Float16* __restrict__ Vf)
{
    __shared__ __align__(16) _Float16 lds[12288];
    _Float16* Xh = lds;              // 2048 halfs
    _Float16* Xl = lds + 2048;       // 2048
    _Float16* Wh = lds + 4096;       // 4096 (4 ct x 2 kt x 64 lanes x 8)
    _Float16* Wl = lds + 8192;       // 4096

    const int tid  = threadIdx.x;
    const int wv   = tid >> 6;
    const int lane = tid & 63;
    const int quad = lane >> 4;
    const int l15  = lane & 15;
    const int r0   = (blockIdx.x & 255) * 32;
    const int cb4  = (blockIdx.x >> 8) * 4;      // coltile base 0,4,8
    const int rt   = wv & 1;
    const int cp   = (wv >> 1) * 2;

    const int xrow = tid >> 3;              // 0..31
    const int xk8  = (tid & 7) * 8;         // 0..56
    const int xslot = (((xrow >> 4) * 2 + (xk8 >> 5)) * 64 +
                       ((xk8 >> 3) & 3) * 16 + (xrow & 15)) * 8;

    f32x4 acc[2];
    acc[0] = (f32x4){0.f, 0.f, 0.f, 0.f};
    acc[1] = (f32x4){0.f, 0.f, 0.f, 0.f};

    float4 pxa, pxb;
    f16x8  pwh[2], pwl2[2];
    {   // prefetch chunk 0
        const float* xp = &X[(size_t)(r0 + xrow) * HH + xk8];
        pxa = *(const float4*)&xp[0];
        pxb = *(const float4*)&xp[4];
#pragma unroll
        for (int i = 0; i < 2; ++i) {
            const int s = tid + i * 256;            // 0..511
            const int ctl = s >> 7, kt = (s >> 6) & 1, ln = s & 63;
            const size_t off = (size_t)(((cb4 + ctl) * 2 + kt) * 64 + ln) * 8;
            pwh[i]  = *(const f16x8*)&Whg[off];
            pwl2[i] = *(const f16x8*)&Wlg[off];
        }
    }

    for (int ch = 0; ch < 16; ++ch) {
        __syncthreads();
        {   // commit prefetched chunk to LDS
            const float xv[8] = {pxa.x, pxa.y, pxa.z, pxa.w,
                                 pxb.x, pxb.y, pxb.z, pxb.w};
            f16x8 hv, lv;
#pragma unroll
            for (int e = 0; e < 8; ++e) {
                const _Float16 h = (_Float16)xv[e];
                hv[e] = h;
                lv[e] = (_Float16)(xv[e] - (float)h);
            }
            *(f16x8*)&Xh[xslot] = hv;
            *(f16x8*)&Xl[xslot] = lv;
#pragma unroll
            for (int i = 0; i < 2; ++i) {
                *(f16x8*)&Wh[(tid + i * 256) * 8] = pwh[i];
                *(f16x8*)&Wl[(tid + i * 256) * 8] = pwl2[i];
            }
        }
        __syncthreads();
        if (ch + 1 < 16) {   // prefetch next chunk (overlaps compute)
            const float* xp = &X[(size_t)(r0 + xrow) * HH + (ch + 1) * 64 + xk8];
            pxa = *(const float4*)&xp[0];
            pxb = *(const float4*)&xp[4];
            const size_t cb = (size_t)(ch + 1) * WCH;
#pragma unroll
            for (int i = 0; i < 2; ++i) {
                const int s = tid + i * 256;
                const int ctl = s >> 7, kt = (s >> 6) & 1, ln = s & 63;
                const size_t off = cb +
                    (size_t)(((cb4 + ctl) * 2 + kt) * 64 + ln) * 8;
                pwh[i]  = *(const f16x8*)&Whg[off];
                pwl2[i] = *(const f16x8*)&Wlg[off];
            }
        }
#pragma unroll
        for (int kt = 0; kt < 2; ++kt) {
            const f16x8 aH = *(const f16x8*)&Xh[((rt * 2 + kt) * 64 + lane) * 8];
            const f16x8 aL = *(const f16x8*)&Xl[((rt * 2 + kt) * 64 + lane) * 8];
#pragma unroll
            for (int cj = 0; cj < 2; ++cj) {
                const int ctl = cp + cj;
                const f16x8 bh = *(const f16x8*)&Wh[((ctl * 2 + kt) * 64 + lane) * 8];
                const f16x8 bl = *(const f16x8*)&Wl[((ctl * 2 + kt) * 64 + lane) * 8];
                acc[cj] = __builtin_amdgcn_mfma_f32_16x16x32_f16(aH, bh, acc[cj], 0, 0, 0);
                acc[cj] = __builtin_amdgcn_mfma_f32_16x16x32_f16(aH, bl, acc[cj], 0, 0, 0);
                acc[cj] = __builtin_amdgcn_mfma_f32_16x16x32_f16(aL, bh, acc[cj], 0, 0, 0);
            }
        }
    }

    // ---- epilogue: descale + xPos (per-chunk renormalized scale) ----
#pragma unroll
    for (int cj = 0; cj < 2; ++cj) {
        const int ctg = cb4 + cp + cj;
        const f32x4 v = acc[cj];
        const int col = ctg * 16 + l15;
        const int mat = ctg >> 2;            // 0=Q 1=K 2=V
        const int d   = col & 63;
        if (mat < 2) {
            const int i2 = d >> 1;
            const float sv   = (2.f * (float)i2 + 25.6f) / 89.6f;
            const float l2sv = log2f(sv);
            const float ifr  = exp2f(-13.28771237954945f * ((float)i2 / 32.f));
            const float sgn  = (mat == 0) ? 1.f : -1.f;
#pragma unroll
            for (int r = 0; r < 4; ++r) {
                const int row = r0 + rt * 16 + quad * 4 + r;
                const float val = v[r] * (1.f / 1024.f);
                const float p = __shfl_xor(val, 1, 64);
                const float pf  = (float)(row & (LL - 1));   // abs pos
                const float pfs = (float)(row & 63);          // renorm
                const float scl = exp2f(sgn * (pfs * (1.f / 512.f)) * l2sv);
                float s, c;
                sincosf(pf * ifr, &s, &c);
                s *= scl; c *= scl;
                const float o = ((col & 1) == 0) ? val * c - p * s
                                                 : val * c + p * s;
                if (mat == 0) {
                    Qr[(size_t)row * DD + d] = (_Float16)o;
                } else {
                    const int b = row >> 12, posb = row & 4095;
                    Kf[(((size_t)b * 8 + (d >> 3)) * 4096 + posb) * 8 + (d & 7)] =
                        (_Float16)o;
                }
            }
        } else {
            f16x4 vv;
#pragma unroll
            for (int r = 0; r < 4; ++r) vv[r] = (_Float16)(v[r] * (1.f / 1024.f));
            const int row0 = r0 + rt * 16 + quad * 4;
            const int b = row0 >> 12, posb = row0 & 4095;
            *(f16x4*)&Vf[(((size_t)b * 512 + (posb >> 3)) * 64 + d) * 8 + (posb & 7)] = vv;
        }
    }
}

// ---------------------------------------------------------------------------
// Kernel 2: chunk output, direct cross-attention over prev 8 chunks.
// grid 512 = (chunk 128) x (row-quarter 4), 256 thr, 4 waves.
// Block = 16 rows. Wave w owns m-range / d'-range w*16..w*16+15.
//   intra:  S[n][m] = (Q.K_m) pwl[n-m] (n>=m)
//   cross:  S[n][64+mc] = (Q.K'') pwl[n],  K'' = K * g^(64D-mq) * sv_d^(D/8)
//   out = S @ V_all (576-k pass, B-frags coalesced from Vf)
// LDS ~20 KB -> high occupancy (2 blocks/CU by grid).
// ---------------------------------------------------------------------------
__global__ __launch_bounds__(256) void chunk_out(
    const _Float16* __restrict__ Qr, const _Float16* __restrict__ Kf,
    const _Float16* __restrict__ Vf, float* __restrict__ out)
{
    __shared__ __align__(16) unsigned char smraw[20032];
    _Float16* Sb  = (_Float16*)smraw;             // 16 x SBS f16 = 18688 B
    _Float16* svp = (_Float16*)(smraw + 18688);   // 512 f16 = 1024 B
    float*    pwl = (float*)(smraw + 19712);      // 65 f32

    const int tid   = threadIdx.x;
    const int bc    = blockIdx.x;
    const int chunk = bc >> 2;
    const int qt    = bc & 3;
    const int w     = tid >> 6;
    const int lane  = tid & 63;
    const int quad  = lane >> 4;
    const int l15   = lane & 15;
    const int cloc  = chunk & 63;
    const int bB    = chunk >> 6;
    const size_t rowbase = (size_t)chunk * CHK + qt * 16;
    const float l2g = log2f(GAMMA);

    if (tid < 65) pwl[tid] = exp2f((float)tid * l2g);
#pragma unroll
    for (int e = 0; e < 2; ++e) {     // svp[(D-1)*64 + d] = sv_d^(D/8)
        const int idx = tid + e * 256;
        const int dl  = (idx >> 6) + 1;
        const int dd  = idx & 63;
        const float sv = (2.f * (float)(dd >> 1) + 25.6f) / 89.6f;
        svp[idx] = (_Float16)exp2f(0.125f * (float)dl * log2f(sv));
    }

    // A-frags (block's 16 Q rows; same for all waves)
    f16x8 aQ[2];
#pragma unroll
    for (int ks = 0; ks < 2; ++ks)
        aQ[ks] = *(const f16x8*)&Qr[(rowbase + l15) * DD + ks * 32 + quad * 8];
    __syncthreads();   // svp, pwl ready

    // ---- phase A intra (wave w: m = w*16..w*16+15) ----
    {
        const int posb = cloc * 64 + w * 16 + l15;
        f32x4 sA = (f32x4){0.f, 0.f, 0.f, 0.f};
#pragma unroll
        for (int ks = 0; ks < 2; ++ks) {
            const f16x8 bK = *(const f16x8*)&Kf[(((size_t)bB * 8 + ks * 4 + quad)
                                                * 4096 + posb) * 8];
            sA = __builtin_amdgcn_mfma_f32_16x16x32_f16(aQ[ks], bK, sA, 0, 0, 0);
        }
        const int m = w * 16 + l15;
#pragma unroll
        for (int r = 0; r < 4; ++r) {
            const int nl = quad * 4 + r;
            const int n64 = qt * 16 + nl;
            const float val = (n64 >= m) ? sA[r] * pwl[n64 - m] : 0.f;
            Sb[nl * SBS + m] = (_Float16)val;
        }
    }

    // ---- phase A cross: 8 jtiles/wave over prev 512 keys ----
    for (int jc = w; jc < 32; jc += 4) {
        const int dlt = 8 - (jc >> 2);                 // chunk distance 1..8
        const bool valid = (dlt <= cloc);
        const int mq = (jc * 16 + l15) & 63;
        const float gl = valid ? exp2f((float)(64 * dlt - mq) * l2g) : 0.f;
        const _Float16 glh = (_Float16)gl;
        const int cs = valid ? (chunk - dlt) : chunk;
        const int posb = (cs & 63) * 64 + mq;
        f32x4 sc4 = (f32x4){0.f, 0.f, 0.f, 0.f};
#pragma unroll
        for (int ks = 0; ks < 2; ++ks) {
            const f16x8 bk = *(const f16x8*)&Kf[(((size_t)bB * 8 + ks * 4 + quad)
                                                * 4096 + posb) * 8];
            const f16x8 sv8 = *(const f16x8*)&svp[(dlt - 1) * 64 + ks * 32 + quad * 8];
            f16x8 b2;
#pragma unroll
            for (int j = 0; j < 8; ++j) b2[j] = bk[j] * glh * sv8[j];
            sc4 = __builtin_amdgcn_mfma_f32_16x16x32_f16(aQ[ks], b2, sc4, 0, 0, 0);
        }
#pragma unroll
        for (int r = 0; r < 4; ++r) {
            const int nl = quad * 4 + r;
            const int na = qt * 16 + nl;
            Sb[nl * SBS + 64 + jc * 16 + l15] = (_Float16)(sc4[r] * pwl[na]);
        }
    }
    __syncthreads();

    // ---- phase B: out = S @ V_all (576 k); wave w: d' = w*16..+15 ----
    f32x4 oA = (f32x4){0.f, 0.f, 0.f, 0.f};
    const int dp = w * 16 + l15;
    for (int ks5 = 0; ks5 < 18; ++ks5) {
        const f16x8 aS = *(const f16x8*)&Sb[l15 * SBS + ks5 * 32 + quad * 8];
        const int m0 = ks5 * 32 + quad * 8;
        int gr;
        if (ks5 < 2) {
            gr = chunk * 64 + m0;
        } else {
            const int mc = m0 - 64;
            int cs2 = chunk - 8 + (mc >> 6);
            if (cs2 < (chunk & ~63)) cs2 = chunk;      // invalid -> S cols are 0
            gr = cs2 * 64 + (mc & 63);
        }
        const int b2 = gr >> 12, pb = gr & 4095;
        const size_t vb = ((size_t)b2 * 512 + (pb >> 3)) * 64;
        const f16x8 bV = *(const f16x8*)&Vf[(vb + dp) * 8];
        oA = __builtin_amdgcn_mfma_f32_16x16x32_f16(aS, bV, oA, 0, 0, 0);
    }
#pragma unroll
    for (int r = 0; r < 4; ++r)
        out[(rowbase + quad * 4 + r) * DD + dp] = oA[r];
}

// ---------------------------------------------------------------------------
extern "C" void kernel_launch(void* const* d_in, const int* in_sizes, int n_in,
                              void* d_out, int out_size, void* d_ws, size_t ws_size,
                              hipStream_t stream)
{
    const float* X  = (const float*)d_in[0];
    const float* WQ = (const float*)d_in[1];
    const float* WK = (const float*)d_in[2];
    const float* WV = (const float*)d_in[3];
    float* outp = (float*)d_out;

    _Float16* Whg = (_Float16*)d_ws;                 // 196608 h
    _Float16* Wlg = Whg + 196608;                    // 196608 h
    _Float16* Qr  = Wlg + 196608;                    // 524288 h
    _Float16* Kf  = Qr + (size_t)BLROWS * DD;        // 524288 h
    _Float16* Vf  = Kf + (size_t)BLROWS * DD;        // 524288 h
    // total ~3.9 MB

    hipLaunchKernelGGL(prep_w, dim3(96), dim3(256), 0, stream,
                       WQ, WK, WV, Whg, Wlg);
    hipLaunchKernelGGL(proj_mfma, dim3(768), dim3(256), 0, stream,
                       X, Whg, Wlg, Qr, Kf, Vf);
    hipLaunchKernelGGL(chunk_out, dim3(512), dim3(256), 0, stream,
                       Qr, Kf, Vf, outp);
}

// Round 11
// 106.666 us; speedup vs baseline: 1.0626x; 1.0277x over previous
//
#include <hip/hip_runtime.h>
#include <math.h>

#define NB 2
#define LL 4096
#define HH 1024
#define DD 64
#define CHK 64
#define NCH 64            /* LL/CHK */
#define BLROWS (NB*LL)    /* 8192 */
#define NCHT (NB*NCH)     /* 128 total chunks */
#define GAMMA 0.96875f

typedef _Float16 f16x8 __attribute__((ext_vector_type(8)));
typedef _Float16 f16x4 __attribute__((ext_vector_type(4)));
typedef float    f32x4 __attribute__((ext_vector_type(4)));

#define WCH 12288   /* Wf frag layout: [16 kchunks][12 ct][2 kt][64 lanes][8] */
#define SBS 584     /* Sb row stride (f16), padded for bank spread */

// ---------------------------------------------------------------------------
// Kernel 0: W (scaled 2^10) -> single fp16, fragment order.
// grid 96 x 256 (24576 f16x8 slots), coalesced stores.
// ---------------------------------------------------------------------------
__global__ __launch_bounds__(256) void prep_w(
    const float* __restrict__ WQ, const float* __restrict__ WK,
    const float* __restrict__ WV, _Float16* __restrict__ Wf)
{
    const unsigned t = blockIdx.x * 256 + threadIdx.x;   // 0..24575
    const unsigned kchunk = t / 1536u;
    const unsigned s = t - kchunk * 1536u;
    const int ct2  = s >> 6;            // (n16)*2 + kt
    const int lane = s & 63;
    const int n16  = ct2 >> 1;
    const int kt   = ct2 & 1;
    const int quad = lane >> 4;
    const int n    = n16 * 16 + (lane & 15);
    const int k0   = (int)kchunk * 64 + kt * 32 + quad * 8;
    const int m    = n >> 6;
    const int d    = n & 63;
    const float* Wm = (m == 0) ? WQ : (m == 1) ? WK : WV;
    f16x8 hv;
#pragma unroll
    for (int j = 0; j < 8; ++j)
        hv[j] = (_Float16)(Wm[(size_t)(k0 + j) * DD + d] * 1024.f);
    *(f16x8*)&Wf[(size_t)t * 8] = hv;
}

// ---------------------------------------------------------------------------
// Kernel 1: MFMA projection, single fp16, BARRIER-FREE, ZERO LDS.
// grid 512 (16-row groups), 256 thr (4 waves). Block = 16 rows x 192 cols;
// wave w owns coltiles 3w..3w+2. A-frags cvt'd in-register from fp32 X;
// B-frags direct 16 B/lane coalesced loads from frag-ordered Wf (L2-hot).
// Register double-buffer on the K-chunk loop; fp32 accumulate.
// Outputs: Qr row-major fp16; Kf frag slabs [b][d>>3][pos][d&7];
//          Vf frag cells [b][pos>>3][d][pos&7].
// ---------------------------------------------------------------------------
__global__ __launch_bounds__(256) void proj_mfma(
    const float* __restrict__ X, const _Float16* __restrict__ Wf,
    _Float16* __restrict__ Qr, _Float16* __restrict__ Kf,
    _Float16* __restrict__ Vf)
{
    const int tid  = threadIdx.x;
    const int wv   = tid >> 6;
    const int lane = tid & 63;
    const int quad = lane >> 4;
    const int l15  = lane & 15;
    const int rg   = blockIdx.x;                 // 0..511
    const size_t xrow = (size_t)(rg * 16 + l15) * HH;

    f32x4 acc[3];
#pragma unroll
    for (int i = 0; i < 3; ++i) acc[i] = (f32x4){0.f, 0.f, 0.f, 0.f};

    float4 pA[4];          // [kt][half]: k = kt*32 + quad*8 + (0..7)
    f16x8  pB[6];          // [cj*2+kt]
    {   // prefetch chunk 0
        const float* xp = &X[xrow + quad * 8];
        pA[0] = *(const float4*)&xp[0];
        pA[1] = *(const float4*)&xp[4];
        pA[2] = *(const float4*)&xp[32];
        pA[3] = *(const float4*)&xp[36];
#pragma unroll
        for (int cj = 0; cj < 3; ++cj)
#pragma unroll
            for (int kt = 0; kt < 2; ++kt)
                pB[cj * 2 + kt] = *(const f16x8*)&Wf[
                    (size_t)((((wv * 3 + cj) * 2 + kt) * 64 + lane)) * 8];
    }

    for (int ch = 0; ch < 16; ++ch) {
        // convert A to fp16 frags
        f16x8 a[2];
#pragma unroll
        for (int kt = 0; kt < 2; ++kt) {
            const float4 xa = pA[kt * 2], xb = pA[kt * 2 + 1];
            a[kt][0] = (_Float16)xa.x; a[kt][1] = (_Float16)xa.y;
            a[kt][2] = (_Float16)xa.z; a[kt][3] = (_Float16)xa.w;
            a[kt][4] = (_Float16)xb.x; a[kt][5] = (_Float16)xb.y;
            a[kt][6] = (_Float16)xb.z; a[kt][7] = (_Float16)xb.w;
        }
        f16x8 b[6];
#pragma unroll
        for (int i = 0; i < 6; ++i) b[i] = pB[i];

        if (ch + 1 < 16) {   // prefetch next chunk (overlaps MFMAs)
            const float* xp = &X[xrow + (ch + 1) * 64 + quad * 8];
            pA[0] = *(const float4*)&xp[0];
            pA[1] = *(const float4*)&xp[4];
            pA[2] = *(const float4*)&xp[32];
            pA[3] = *(const float4*)&xp[36];
            const size_t cb = (size_t)(ch + 1) * WCH;
#pragma unroll
            for (int cj = 0; cj < 3; ++cj)
#pragma unroll
                for (int kt = 0; kt < 2; ++kt)
                    pB[cj * 2 + kt] = *(const f16x8*)&Wf[cb +
                        (size_t)((((wv * 3 + cj) * 2 + kt) * 64 + lane)) * 8];
        }
#pragma unroll
        for (int kt = 0; kt < 2; ++kt)
#pragma unroll
            for (int cj = 0; cj < 3; ++cj)
                acc[cj] = __builtin_amdgcn_mfma_f32_16x16x32_f16(
                    a[kt], b[cj * 2 + kt], acc[cj], 0, 0, 0);
    }

    // ---- epilogue: descale + xPos (per-chunk renormalized scale) ----
#pragma unroll
    for (int cj = 0; cj < 3; ++cj) {
        const int ctg = wv * 3 + cj;
        const f32x4 v = acc[cj];
        const int col = ctg * 16 + l15;
        const int mat = ctg >> 2;            // 0=Q 1=K 2=V
        const int d   = col & 63;
        if (mat < 2) {
            const int i2 = d >> 1;
            const float sv   = (2.f * (float)i2 + 25.6f) / 89.6f;
            const float l2sv = log2f(sv);
            const float ifr  = exp2f(-13.28771237954945f * ((float)i2 / 32.f));
            const float sgn  = (mat == 0) ? 1.f : -1.f;
#pragma unroll
            for (int r = 0; r < 4; ++r) {
                const int row = rg * 16 + quad * 4 + r;
                const float val = v[r] * (1.f / 1024.f);
                const float p = __shfl_xor(val, 1, 64);
                const float pf  = (float)(row & (LL - 1));   // abs pos
                const float pfs = (float)(row & 63);          // renorm
                const float scl = exp2f(sgn * (pfs * (1.f / 512.f)) * l2sv);
                float s, c;
                sincosf(pf * ifr, &s, &c);
                s *= scl; c *= scl;
                const float o = ((col & 1) == 0) ? val * c - p * s
                                                 : val * c + p * s;
                if (mat == 0) {
                    Qr[(size_t)row * DD + d] = (_Float16)o;
                } else {
                    const int b2 = row >> 12, posb = row & 4095;
                    Kf[(((size_t)b2 * 8 + (d >> 3)) * 4096 + posb) * 8 + (d & 7)] =
                        (_Float16)o;
                }
            }
        } else {
            f16x4 vv;
#pragma unroll
            for (int r = 0; r < 4; ++r) vv[r] = (_Float16)(v[r] * (1.f / 1024.f));
            const int row0 = rg * 16 + quad * 4;
            const int b2 = row0 >> 12, posb = row0 & 4095;
            *(f16x4*)&Vf[(((size_t)b2 * 512 + (posb >> 3)) * 64 + d) * 8 + (posb & 7)] = vv;
        }
    }
}

// ---------------------------------------------------------------------------
// Kernel 2: chunk output, direct cross-attention over prev 8 chunks.
// grid 512 = (chunk 128) x (row-quarter 4), 256 thr, 4 waves. (R10, verified)
// ---------------------------------------------------------------------------
__global__ __launch_bounds__(256) void chunk_out(
    const _Float16* __restrict__ Qr, const _Float16* __restrict__ Kf,
    const _Float16* __restrict__ Vf, float* __restrict__ out)
{
    __shared__ __align__(16) unsigned char smraw[20032];
    _Float16* Sb  = (_Float16*)smraw;             // 16 x SBS f16 = 18688 B
    _Float16* svp = (_Float16*)(smraw + 18688);   // 512 f16 = 1024 B
    float*    pwl = (float*)(smraw + 19712);      // 65 f32

    const int tid   = threadIdx.x;
    const int bc    = blockIdx.x;
    const int chunk = bc >> 2;
    const int qt    = bc & 3;
    const int w     = tid >> 6;
    const int lane  = tid & 63;
    const int quad  = lane >> 4;
    const int l15   = lane & 15;
    const int cloc  = chunk & 63;
    const int bB    = chunk >> 6;
    const size_t rowbase = (size_t)chunk * CHK + qt * 16;
    const float l2g = log2f(GAMMA);

    if (tid < 65) pwl[tid] = exp2f((float)tid * l2g);
#pragma unroll
    for (int e = 0; e < 2; ++e) {     // svp[(D-1)*64 + d] = sv_d^(D/8)
        const int idx = tid + e * 256;
        const int dl  = (idx >> 6) + 1;
        const int dd  = idx & 63;
        const float sv = (2.f * (float)(dd >> 1) + 25.6f) / 89.6f;
        svp[idx] = (_Float16)exp2f(0.125f * (float)dl * log2f(sv));
    }

    // A-frags (block's 16 Q rows; same for all waves)
    f16x8 aQ[2];
#pragma unroll
    for (int ks = 0; ks < 2; ++ks)
        aQ[ks] = *(const f16x8*)&Qr[(rowbase + l15) * DD + ks * 32 + quad * 8];
    __syncthreads();   // svp, pwl ready

    // ---- phase A intra (wave w: m = w*16..w*16+15) ----
    {
        const int posb = cloc * 64 + w * 16 + l15;
        f32x4 sA = (f32x4){0.f, 0.f, 0.f, 0.f};
#pragma unroll
        for (int ks = 0; ks < 2; ++ks) {
            const f16x8 bK = *(const f16x8*)&Kf[(((size_t)bB * 8 + ks * 4 + quad)
                                                * 4096 + posb) * 8];
            sA = __builtin_amdgcn_mfma_f32_16x16x32_f16(aQ[ks], bK, sA, 0, 0, 0);
        }
        const int m = w * 16 + l15;
#pragma unroll
        for (int r = 0; r < 4; ++r) {
            const int nl = quad * 4 + r;
            const int n64 = qt * 16 + nl;
            const float val = (n64 >= m) ? sA[r] * pwl[n64 - m] : 0.f;
            Sb[nl * SBS + m] = (_Float16)val;
        }
    }

    // ---- phase A cross: 8 jtiles/wave over prev 512 keys ----
    for (int jc = w; jc < 32; jc += 4) {
        const int dlt = 8 - (jc >> 2);                 // chunk distance 1..8
        const bool valid = (dlt <= cloc);
        const int mq = (jc * 16 + l15) & 63;
        const float gl = valid ? exp2f((float)(64 * dlt - mq) * l2g) : 0.f;
        const _Float16 glh = (_Float16)gl;
        const int cs = valid ? (chunk - dlt) : chunk;
        const int posb = (cs & 63) * 64 + mq;
        f32x4 sc4 = (f32x4){0.f, 0.f, 0.f, 0.f};
#pragma unroll
        for (int ks = 0; ks < 2; ++ks) {
            const f16x8 bk = *(const f16x8*)&Kf[(((size_t)bB * 8 + ks * 4 + quad)
                                                * 4096 + posb) * 8];
            const f16x8 sv8 = *(const f16x8*)&svp[(dlt - 1) * 64 + ks * 32 + quad * 8];
            f16x8 b2;
#pragma unroll
            for (int j = 0; j < 8; ++j) b2[j] = bk[j] * glh * sv8[j];
            sc4 = __builtin_amdgcn_mfma_f32_16x16x32_f16(aQ[ks], b2, sc4, 0, 0, 0);
        }
#pragma unroll
        for (int r = 0; r < 4; ++r) {
            const int nl = quad * 4 + r;
            const int na = qt * 16 + nl;
            Sb[nl * SBS + 64 + jc * 16 + l15] = (_Float16)(sc4[r] * pwl[na]);
        }
    }
    __syncthreads();

    // ---- phase B: out = S @ V_all (576 k); wave w: d' = w*16..+15 ----
    f32x4 oA = (f32x4){0.f, 0.f, 0.f, 0.f};
    const int dp = w * 16 + l15;
    for (int ks5 = 0; ks5 < 18; ++ks5) {
        const f16x8 aS = *(const f16x8*)&Sb[l15 * SBS + ks5 * 32 + quad * 8];
        const int m0 = ks5 * 32 + quad * 8;
        int gr;
        if (ks5 < 2) {
            gr = chunk * 64 + m0;
        } else {
            const int mc = m0 - 64;
            int cs2 = chunk - 8 + (mc >> 6);
            if (cs2 < (chunk & ~63)) cs2 = chunk;      // invalid -> S cols are 0
            gr = cs2 * 64 + (mc & 63);
        }
        const int b2 = gr >> 12, pb = gr & 4095;
        const size_t vb = ((size_t)b2 * 512 + (pb >> 3)) * 64;
        const f16x8 bV = *(const f16x8*)&Vf[(vb + dp) * 8];
        oA = __builtin_amdgcn_mfma_f32_16x16x32_f16(aS, bV, oA, 0, 0, 0);
    }
#pragma unroll
    for (int r = 0; r < 4; ++r)
        out[(rowbase + quad * 4 + r) * DD + dp] = oA[r];
}

// ---------------------------------------------------------------------------
extern "C" void kernel_launch(void* const* d_in, const int* in_sizes, int n_in,
                              void* d_out, int out_size, void* d_ws, size_t ws_size,
                              hipStream_t stream)
{
    const float* X  = (const float*)d_in[0];
    const float* WQ = (const float*)d_in[1];
    const float* WK = (const float*)d_in[2];
    const float* WV = (const float*)d_in[3];
    float* outp = (float*)d_out;

    _Float16* Wf = (_Float16*)d_ws;                  // 196608 h
    _Float16* Qr = Wf + 196608;                      // 524288 h
    _Float16* Kf = Qr + (size_t)BLROWS * DD;         // 524288 h
    _Float16* Vf = Kf + (size_t)BLROWS * DD;         // 524288 h
    // total ~3.5 MB

    hipLaunchKernelGGL(prep_w, dim3(96), dim3(256), 0, stream,
                       WQ, WK, WV, Wf);
    hipLaunchKernelGGL(proj_mfma, dim3(512), dim3(256), 0, stream,
                       X, Wf, Qr, Kf, Vf);
    hipLaunchKernelGGL(chunk_out, dim3(512), dim3(256), 0, stream,
                       Qr, Kf, Vf, outp);
}